// Round 9
// baseline (6107.671 us; speedup 1.0000x reference)
//
#include <hip/hip_runtime.h>
#include <cstddef>
#include <math.h>

// Problem: B=64, S=1024, F=128, H=512, V=64, T=64. f32 in/out.
// R15 = R14 (proven 5015us, absmax 0.031) + fan-out halved via 2-tile waves:
//  - Evidence: R14 halved far volume for only -6% -> serial coherence-trip
//    chain dominates, stretched by in-flight transaction count. Biggest
//    remaining knob: consumer fan-out (32 consumers x 16KB tile re-fetch).
//  - W_hh residency math: 1 tile (16 dims, hi+lo) = 128 VGPR; at 1 wave/SIMD
//    (512 budget) a wave holds TWO tiles (256 + ~130 working < 512). So:
//    16 WGs/group (each 32 dims/gate), 64 WGs total. Far transactions/step
//    halve, flag fan 32->16, cell h-store = ONE packed u32/thread (2 adjacent
//    dims, no shfl).
//  - Everything else R14-identical: f16-only h exchange (W hi+lo), flag
//    protocol on sc0|sc1 coherence path, coalesced conflict-free STAGE_H,
//    x-part(t+1) pipelined over the store-ack, same ws layout.
#define NGROUP 4
#define WPG    16
#define NWG    64
#define BPG    16
#define HH  512
#define TT  64
#define VV  64
#define FF  128
#define SS  1024

typedef _Float16 f16;
typedef _Float16 f16x8 __attribute__((ext_vector_type(8)));
typedef float    f32x4 __attribute__((ext_vector_type(4)));
typedef unsigned int u32;
typedef unsigned short u16;
typedef u32 u32x4 __attribute__((ext_vector_type(4)));
typedef unsigned long long u64;

#define C1 4.8828125e-4f          // 2^-11
#define C2 2.384185791015625e-7f  // 2^-22

__device__ __forceinline__ void split8(const float* __restrict__ p, f16x8& hi, f16x8& lo) {
  f32x4 u = *(const f32x4*)p;
  f32x4 v = *(const f32x4*)(p + 4);
#pragma unroll
  for (int j = 0; j < 4; ++j) {
    f16 a = (f16)u[j]; hi[j]   = a; lo[j]   = (f16)((u[j] - (float)a) * 2048.0f);
    f16 b = (f16)v[j]; hi[4+j] = b; lo[4+j] = (f16)((v[j] - (float)b) * 2048.0f);
  }
}
__device__ __forceinline__ float sigmf_(float x) { return 1.0f / (1.0f + expf(-x)); }

// far (coherence-point) accessors — R4/R8/R13/R14-proven pattern
__device__ __forceinline__ f32x4 ld16f(const void* p) {
  f32x4 r;
  asm volatile("global_load_dwordx4 %0, %1, off sc0 sc1" : "=v"(r) : "v"(p) : "memory");
  return r;
}
__device__ __forceinline__ void st4f(u32* p, u32 v) {
  __hip_atomic_store(p, v, __ATOMIC_RELAXED, __HIP_MEMORY_SCOPE_AGENT);
}
__device__ __forceinline__ void st8f(u64* p, u64 v) {
  __hip_atomic_store(p, v, __ATOMIC_RELAXED, __HIP_MEMORY_SCOPE_AGENT);
}
__device__ __forceinline__ u32 ld4f(const u32* p) {
  return __hip_atomic_load(p, __ATOMIC_RELAXED, __HIP_MEMORY_SCOPE_AGENT);
}
#define VMWAIT asm volatile("s_waitcnt vmcnt(0)" ::: "memory")

// barrier: poll this group's 16 per-WG flags with one gather (lanes mod 16)
__device__ __forceinline__ void wait_flags(const u32* flags, u32 target, int lane) {
  const u32* a = flags + (size_t)(lane & 15) * 32;   // 128B stride
  while (!__all(ld4f(a) >= target))
    __builtin_amdgcn_s_sleep(1);
}

#define MFMA(d, a, b) d = __builtin_amdgcn_mfma_f32_16x16x32_f16(a, b, d, 0, 0, 0)

// one-shot h stage: group tile [16][256] u32 (f16 dim pairs) -> LDS f16.
// Thread (r=tid>>4, cq=tid&15), chunk u2: u32 cols cq*4+u2*64 of row r.
// Per instruction: 16 same-row lanes contiguous 256B (coalesced far reads);
// LDS write u32x4 at (r*1024 + cq*16 + u2*256) ^ ((r&7)<<4): conflict-free.
// rule #18: tie values through volatile asm + sched_barrier after VMWAIT.
#define STAGE_H(src_)                                                         \
  { const u32* src = (src_) + (size_t)(tid >> 4) * 256;                       \
    const int cq_ = tid & 15;                                                 \
    f32x4 sv[4];                                                              \
    _Pragma("unroll") for (int u2 = 0; u2 < 4; ++u2)                          \
      sv[u2] = ld16f(src + cq_*4 + u2*64);                                    \
    VMWAIT;                                                                   \
    _Pragma("unroll") for (int u2 = 0; u2 < 4; ++u2)                          \
      asm volatile("" : "+v"(sv[u2]));                                        \
    __builtin_amdgcn_sched_barrier(0);                                        \
    const int r_ = tid >> 4;                                                  \
    const size_t swz = (size_t)((r_ & 7) << 4);                               \
    _Pragma("unroll") for (int u2 = 0; u2 < 4; ++u2) {                        \
      size_t off = ((size_t)r_*1024 + (size_t)cq_*16 + (size_t)u2*256) ^ swz; \
      *(u32x4*)((char*)sh_h + off) = __builtin_bit_cast(u32x4, sv[u2]);       \
    } }                                                                       \
  __syncthreads();

// A-fragment read (row = batch mn, k-slice s), same swizzle as write side
#define LDA(s, ah)                                                            \
  { size_t o_ = ((size_t)mn * 1024 + (size_t)(s) * 64 + (size_t)(q8 * 2))     \
                ^ (size_t)((mn & 7) << 4);                                    \
    ah = *(const f16x8*)((const char*)sh_h + o_); }

// h-part: h f16-only; per k-slice ONE A-frag feeds both weight tiles.
#define HPART()                                                               \
  _Pragma("unroll") for (int s = 0; s < 16; ++s) {                            \
    f16x8 ah; LDA(s, ah);                                                     \
    _Pragma("unroll") for (int j = 0; j < 2; ++j) {                           \
      MFMA(acc0[j], ah, whh_h[j][s]);                                         \
      MFMA(acc1[j], ah, whh_l[j][s]);                                         \
    } }

// x-part for sig row ts (full Ootomo), (re)initializes acc0..2
#define XPART(ts)                                                             \
  { _Pragma("unroll") for (int j = 0; j < 2; ++j) {                           \
      acc0[j] = zero4; acc1[j] = zero4; acc2[j] = zero4; }                    \
    const float* sb = sig + (size_t)(gb + mn) * (SS * FF) + (size_t)(ts) * FF;\
    _Pragma("unroll") for (int s = 0; s < 4; ++s) {                           \
      f16x8 xh, xl;                                                           \
      split8(sb + s * 32 + q8, xh, xl);                                       \
      _Pragma("unroll") for (int j = 0; j < 2; ++j) {                         \
        MFMA(acc0[j], xh, wih_h[j][s]);                                       \
        MFMA(acc1[j], xl, wih_h[j][s]);                                       \
        MFMA(acc1[j], xh, wih_l[j][s]);                                       \
        MFMA(acc2[j], xl, wih_l[j][s]);                                       \
      } } }

// C/D layout: col = lane&15 = dim within tile j, row = (lane>>4)*4 + r = batch
#define GWRITE()                                                              \
  _Pragma("unroll") for (int j = 0; j < 2; ++j)                               \
    _Pragma("unroll") for (int r = 0; r < 4; ++r)                             \
      gate_buf[w][q*4 + r][j*16 + mn] = acc0[j][r] + C1*acc1[j][r] + C2*acc2[j][r];

__global__ void __launch_bounds__(256, 1) lstm_seq2seq(
    const float* __restrict__ sig,   // [B,S,F]
    const int*   __restrict__ tgt,   // [B,T]
    const float* __restrict__ eWih,  // [2048,128]
    const float* __restrict__ eWhh,  // [2048,512]
    const float* __restrict__ eBih,  // [2048]
    const float* __restrict__ eBhh,  // [2048]
    const float* __restrict__ dWih,  // [2048,64]
    const float* __restrict__ dWhh,  // [2048,512]
    const float* __restrict__ dBih,  // [2048]
    const float* __restrict__ dBhh,  // [2048]
    const float* __restrict__ oW,    // [64,512]
    const float* __restrict__ oB,    // [64]
    float*       __restrict__ out,   // [B,T,V]
    unsigned char* __restrict__ ws)
{
  // ws layout (bytes, identical to R14): [0,16384) flags 4 groups x 32 slots
  // x 128B (only 16 used/group); [16384,16640) idxbuf u32[64];
  // [20480,151552) h16 4 groups x 2 buf x 16KB u32 {f16 2j | f16 2j+1 <<16};
  // [151552,282624) hf32 4 groups x 32KB. Zeroed region = [0,151552).
  const int wg = blockIdx.x;
  const int g  = wg >> 4;            // batch group
  const int p  = wg & 15;            // dim slice [p*32, p*32+32) per gate
  const int gb = g * BPG;            // global batch base
  u32* fl     = (u32*)ws + (size_t)g * 1024;
  u32* idxbuf = (u32*)(ws + 16384);
  u32* h16[2] = { (u32*)(ws + 20480) + (size_t)(g*2 + 0) * 4096,
                  (u32*)(ws + 20480) + (size_t)(g*2 + 1) * 4096 };
  float* hfg  = (float*)(ws + 151552) + (size_t)g * 8192;

  const int tid  = threadIdx.x;
  const int w    = tid >> 6;         // wave = gate (i,f,g,o)
  const int lane = tid & 63;
  const int q    = lane >> 4;
  const int mn   = lane & 15;
  const int q8   = q * 8;
  const int row0 = w * HH + p * 32 + mn;   // weight rows for the 2 B-frags
  const int row1 = row0 + 16;
  const int cb   = tid >> 4;         // cell: local batch 0..15
  const int ck   = tid & 15;         // cell: dim-pair within slice
  const int crow0 = p * 32 + 2 * ck; // cell: h-dims (pair)
  const int crow1 = crow0 + 1;

  __shared__ __attribute__((aligned(16))) f16 sh_h[16 * 512]; // 16KB swizzled
  __shared__ float gate_buf[4][16][35];
  __shared__ float bias_buf[4][32];
  __shared__ __attribute__((aligned(16))) float hrow[512];
  __shared__ double psum[64];

  // ---- weights: W_hh and W_ih hi/lo fragments in registers (2 tiles) ----
  f16x8 whh_h[2][16], whh_l[2][16], wih_h[2][4], wih_l[2][4];
#pragma unroll
  for (int s = 0; s < 16; ++s) {
    split8(eWhh + (size_t)row0 * HH + s * 32 + q8, whh_h[0][s], whh_l[0][s]);
    split8(eWhh + (size_t)row1 * HH + s * 32 + q8, whh_h[1][s], whh_l[1][s]);
  }
#pragma unroll
  for (int s = 0; s < 4; ++s) {
    split8(eWih + (size_t)row0 * FF + s * 32 + q8, wih_h[0][s], wih_l[0][s]);
    split8(eWih + (size_t)row1 * FF + s * 32 + q8, wih_h[1][s], wih_l[1][s]);
  }
  if (tid < 128) {
    int g4 = tid >> 5, kl = tid & 31;
    int r = g4 * HH + p * 32 + kl;
    bias_buf[g4][kl] = eBih[r] + eBhh[r];
  }
  if (p == 0 && tid < BPG)
    st4f(idxbuf + gb + tid, (u32)tgt[(size_t)(gb + tid) * TT]);  // target[:,0]
  __syncthreads();

  float c_reg0 = 0.f, c_reg1 = 0.f;
  int cur = 0;                       // h dbuf (zeroed by memset = h0)
  const f32x4 zero4 = {0.f, 0.f, 0.f, 0.f};
  f32x4 acc0[2], acc1[2], acc2[2];

  // ================= encoder: 1024 steps (x-part pipelined) =================
  XPART(0)
  for (int t = 0; t < SS; ++t) {
    wait_flags(fl, (u32)t, lane);
    STAGE_H(h16[cur])
    HPART()
    GWRITE()
    __syncthreads();
    // LSTM cell: 2 h-values per thread (f32, precise libm)
    {
      float gi0 = gate_buf[0][cb][2*ck]   + bias_buf[0][2*ck];
      float gf0 = gate_buf[1][cb][2*ck]   + bias_buf[1][2*ck];
      float gg0 = gate_buf[2][cb][2*ck]   + bias_buf[2][2*ck];
      float go0 = gate_buf[3][cb][2*ck]   + bias_buf[3][2*ck];
      float gi1 = gate_buf[0][cb][2*ck+1] + bias_buf[0][2*ck+1];
      float gf1 = gate_buf[1][cb][2*ck+1] + bias_buf[1][2*ck+1];
      float gg1 = gate_buf[2][cb][2*ck+1] + bias_buf[2][2*ck+1];
      float go1 = gate_buf[3][cb][2*ck+1] + bias_buf[3][2*ck+1];
      float c0 = sigmf_(gf0) * c_reg0 + sigmf_(gi0) * tanhf(gg0);
      float c1 = sigmf_(gf1) * c_reg1 + sigmf_(gi1) * tanhf(gg1);
      float h0 = sigmf_(go0) * tanhf(c0);
      float h1 = sigmf_(go1) * tanhf(c1);
      c_reg0 = c0; c_reg1 = c1;
      u32 pk = (u32)__builtin_bit_cast(u16, (f16)h0)
             | ((u32)__builtin_bit_cast(u16, (f16)h1) << 16);
      st4f(h16[cur ^ 1] + (size_t)cb * 256 + p * 16 + ck, pk);
    }
    // x-part(t+1) overlaps the h-store ack (clamped: t=SS-1 result unused)
    XPART(t + 1 < SS ? t + 1 : SS - 1)
    VMWAIT;             // h store acked at coherence point (+ sig drained)
    __syncthreads();
    if (tid == 0) st4f(fl + p * 32, (u32)(t + 1));
    cur ^= 1;
  }

  // ================= decoder setup =================
#pragma unroll
  for (int s = 0; s < 16; ++s) {
    split8(dWhh + (size_t)row0 * HH + s * 32 + q8, whh_h[0][s], whh_l[0][s]);
    split8(dWhh + (size_t)row1 * HH + s * 32 + q8, whh_h[1][s], whh_l[1][s]);
  }
  __syncthreads();
  if (tid < 128) {
    int g4 = tid >> 5, kl = tid & 31;
    int r = g4 * HH + p * 32 + kl;
    bias_buf[g4][kl] = dBih[r] + dBhh[r];
  }
  __syncthreads();

  // ================= decoder: 64 steps =================
  for (int t = 0; t < TT; ++t) {
    // ---- phase A: cell. x = one_hot(idx) -> column gather at cell stage ----
    wait_flags(fl, (u32)(SS + 2 * t), lane);
#pragma unroll
    for (int j = 0; j < 2; ++j) { acc0[j] = zero4; acc1[j] = zero4; acc2[j] = zero4; }
    STAGE_H(h16[cur])
    HPART()
    GWRITE()
    __syncthreads();
    {
      int ib = (int)ld4f(idxbuf + gb + cb);
      float gi0 = gate_buf[0][cb][2*ck]   + bias_buf[0][2*ck]   + dWih[(size_t)(0*HH + crow0) * VV + ib];
      float gf0 = gate_buf[1][cb][2*ck]   + bias_buf[1][2*ck]   + dWih[(size_t)(1*HH + crow0) * VV + ib];
      float gg0 = gate_buf[2][cb][2*ck]   + bias_buf[2][2*ck]   + dWih[(size_t)(2*HH + crow0) * VV + ib];
      float go0 = gate_buf[3][cb][2*ck]   + bias_buf[3][2*ck]   + dWih[(size_t)(3*HH + crow0) * VV + ib];
      float gi1 = gate_buf[0][cb][2*ck+1] + bias_buf[0][2*ck+1] + dWih[(size_t)(0*HH + crow1) * VV + ib];
      float gf1 = gate_buf[1][cb][2*ck+1] + bias_buf[1][2*ck+1] + dWih[(size_t)(1*HH + crow1) * VV + ib];
      float gg1 = gate_buf[2][cb][2*ck+1] + bias_buf[2][2*ck+1] + dWih[(size_t)(2*HH + crow1) * VV + ib];
      float go1 = gate_buf[3][cb][2*ck+1] + bias_buf[3][2*ck+1] + dWih[(size_t)(3*HH + crow1) * VV + ib];
      float c0 = sigmf_(gf0) * c_reg0 + sigmf_(gi0) * tanhf(gg0);
      float c1 = sigmf_(gf1) * c_reg1 + sigmf_(gi1) * tanhf(gg1);
      float h0 = sigmf_(go0) * tanhf(c0);
      float h1 = sigmf_(go1) * tanhf(c1);
      c_reg0 = c0; c_reg1 = c1;
      u32 pk = (u32)__builtin_bit_cast(u16, (f16)h0)
             | ((u32)__builtin_bit_cast(u16, (f16)h1) << 16);
      st4f(h16[cur ^ 1] + (size_t)cb * 256 + p * 16 + ck, pk);
      u64 pf = (u64)__builtin_bit_cast(u32, h0)
             | ((u64)__builtin_bit_cast(u32, h1) << 32);
      st8f((u64*)(hfg + (size_t)cb * HH + crow0), pf);
    }
    VMWAIT;
    __syncthreads();
    if (tid == 0) st4f(fl + p * 32, (u32)(SS + 2 * t + 1));
    int nxt = cur ^ 1;

    // ---- phase B: f64 logits + log_softmax + argmax (WG p = batch gb+p) ----
    wait_flags(fl, (u32)(SS + 2 * t + 1), lane);
    if (p < BPG) {
      if (tid < 128) {
        f32x4 hv = ld16f(hfg + (size_t)p * HH + tid * 4);
        VMWAIT;
        *(f32x4*)&hrow[tid * 4] = hv;
      }
      __syncthreads();
      double acc = 0.0;
      if (w < 2) {                   // waves 0,1 split K=512 in halves
        const float* wr = oW + (size_t)lane * HH + w * 256;
        const float* hr = hrow + w * 256;
#pragma unroll 4
        for (int kc = 0; kc < 64; ++kc) {
          f32x4 hv = *(const f32x4*)(hr + kc * 4);
          f32x4 wv = *(const f32x4*)(wr + kc * 4);
          acc += (double)hv[0]*(double)wv[0] + (double)hv[1]*(double)wv[1]
               + (double)hv[2]*(double)wv[2] + (double)hv[3]*(double)wv[3];
        }
        if (w == 1) psum[lane] = acc;
      }
      __syncthreads();
      if (w == 0) {
        double l = acc + psum[lane] + (double)oB[lane];
        double mx = l; int ai = lane;
#pragma unroll
        for (int o = 32; o > 0; o >>= 1) {
          double om = __shfl_xor(mx, o, 64);
          int    oi = __shfl_xor(ai, o, 64);
          if (om > mx || (om == mx && oi < ai)) { mx = om; ai = oi; }
        }
        double se = exp(l - mx);
#pragma unroll
        for (int o = 32; o > 0; o >>= 1) se += __shfl_xor(se, o, 64);
        double lse = mx + log(se);
        out[((size_t)(gb + p) * TT + t) * VV + lane] = (float)(l - lse);
        if (lane == 0) st4f(idxbuf + gb + p, (u32)ai);
      }
    }
    VMWAIT;
    __syncthreads();
    if (tid == 0) st4f(fl + p * 32, (u32)(SS + 2 * t + 2));
    cur = nxt;
  }
}

extern "C" void kernel_launch(void* const* d_in, const int* in_sizes, int n_in,
                              void* d_out, int out_size, void* d_ws, size_t ws_size,
                              hipStream_t stream) {
  (void)in_sizes; (void)n_in; (void)out_size; (void)ws_size;
  // zero: flags + idxbuf + h16 dbufs (ws re-poisoned 0xAA before every timed
  // launch -> must zero every call). hf32 fully written before read.
  hipMemsetAsync(d_ws, 0, 151552, stream);
  lstm_seq2seq<<<dim3(NWG), dim3(256), 0, stream>>>(
      (const float*)d_in[0],  (const int*)d_in[1],
      (const float*)d_in[2],  (const float*)d_in[3],
      (const float*)d_in[4],  (const float*)d_in[5],
      (const float*)d_in[6],  (const float*)d_in[7],
      (const float*)d_in[8],  (const float*)d_in[9],
      (const float*)d_in[10], (const float*)d_in[11],
      (float*)d_out, (unsigned char*)d_ws);
}